// Round 12
// baseline (405.540 us; speedup 1.0000x reference)
//
#include <hip/hip_runtime.h>

#define N_NODES 10000
#define N_EDGES 640000

__device__ __forceinline__ float bf2f(unsigned int u) {
    union { unsigned int i; float f; } v; v.i = u << 16; return v.f;
}
__device__ __forceinline__ unsigned short f2bf(float f) {
    union { float f; unsigned int i; } v; v.f = f;
    unsigned int x = v.i;
    return (unsigned short)((x + 0x7fffu + ((x >> 16) & 1u)) >> 16);
}
__device__ __forceinline__ float scrub(float v) {
    return (v == v && fabsf(v) < 1e6f) ? v : 0.f;
}

// dtype-branched load of float tensor element i
template <bool BF16>
__device__ __forceinline__ float ldf(const void* p, int i) {
    if (BF16) return scrub(bf2f(((const unsigned short*)p)[i]));
    else      return scrub(((const float*)p)[i]);
}

// per-wave edge-dtype detection (validated r11)
__device__ __forceinline__ int edge_step(int hi_word) {
    return (__ballot(hi_word != 0) != 0ull) ? 1 : 2;
}

// ---- K1: degree counts (byte-identical to r11) ----
__global__ __launch_bounds__(256) void k_count(const int* __restrict__ ei,
                                               int* __restrict__ cnt0,
                                               int* __restrict__ cnt1) {
    int e = blockIdx.x * 256 + threadIdx.x;        // always < N_EDGES
    int step = edge_step(ei[2 * e + 1]);
    int s = ei[e * step];
    int d = ei[N_EDGES * step + e * step];
    if ((unsigned)s >= N_NODES || (unsigned)d >= N_NODES) return;
    atomicAdd(&cnt0[d], 1);   // dir0: aggregate x[src] at dst
    atomicAdd(&cnt1[s], 1);   // dir1: aggregate x[dst] at src
}

// ---- K2: shfl exclusive scan + sentinel + dflag (byte-identical to r11) ----
__global__ __launch_bounds__(1024) void k_scan(const int* __restrict__ cnt_base,
                                               int* __restrict__ off_base,
                                               const unsigned int* __restrict__ xw,
                                               int* __restrict__ dflag) {
    const int* cnt = cnt_base + blockIdx.x * N_NODES;
    int* off = off_base + blockIdx.x * (N_NODES + 1);
    __shared__ int wsum[16];
    __shared__ int wexc[16];
    __shared__ int dcnt_s;
    int t = threadIdx.x;
    int lane = t & 63, wid = t >> 6;
    int c[10];
    int s = 0;
    int base_i = t * 10;
#pragma unroll
    for (int i = 0; i < 10; ++i) {
        int idx = base_i + i;
        c[i] = (idx < N_NODES) ? cnt[idx] : 0;
        s += c[i];
    }
    int v = s;
    for (int d = 1; d < 64; d <<= 1) {
        int u = __shfl_up(v, d, 64);
        if (lane >= d) v += u;
    }
    if (lane == 63) wsum[wid] = v;
    __syncthreads();
    if (t < 16) {
        int acc = 0;
        for (int i = 0; i < t; ++i) acc += wsum[i];
        wexc[t] = acc;
    }
    __syncthreads();
    int run = wexc[wid] + (v - s);
#pragma unroll
    for (int i = 0; i < 10; ++i) {
        int idx = base_i + i;
        if (idx < N_NODES) off[idx] = run;
        run += c[i];
    }
    if (t == 1023) off[N_NODES] = run;

    if (blockIdx.x == 0) {
        if (t == 0) dcnt_s = 0;
        __syncthreads();
        int good = 0;
        for (int i = t; i < 4096; i += 1024) {
            unsigned int e = (xw[i] >> 7) & 0xFFu;
            if (e >= 96u && e <= 160u) good++;
        }
        atomicAdd(&dcnt_s, good);
        __syncthreads();
        if (t == 0) dflag[0] = (dcnt_s > 2458) ? 1 : 0;   // >60% -> bf16
    }
}

// ---- K3: fill both CSR buckets (byte-identical to r11) ----
__global__ __launch_bounds__(256) void k_fill_both(const int* __restrict__ ei,
                                                   const int* __restrict__ off0,
                                                   const int* __restrict__ off1,
                                                   int* __restrict__ cnt0,
                                                   int* __restrict__ cnt1,
                                                   int* __restrict__ adj0,
                                                   int* __restrict__ adj1) {
    int e = blockIdx.x * 256 + threadIdx.x;
    int step = edge_step(ei[2 * e + 1]);
    int s = ei[e * step];
    int d = ei[N_EDGES * step + e * step];
    if ((unsigned)s >= N_NODES || (unsigned)d >= N_NODES) return;
    int p0 = atomicSub(&cnt0[d], 1) - 1;
    int p1 = atomicSub(&cnt1[s], 1) - 1;
    adj0[off0[d] + p0] = s;
    adj1[off1[s] + p1] = d;
}

// ---- K4 (r12): 4 nodes/block dual-direction aggemm ----
// Phase 1: lane-per-u32 gather (2 dims/lane, half the VMEM instrs).
// Phase 2: each thread serves 2 rows per W load (half the W VMEM instrs).
template <bool BF16>
__device__ __forceinline__ void gather_pair(const void* x, const int* adj,
                                            int o, int c, int lane,
                                            float* out_lo, float* out_hi) {
    float lo0 = 0.f, lo1 = 0.f, lo2 = 0.f, lo3 = 0.f;
    float hi0 = 0.f, hi1 = 0.f, hi2 = 0.f, hi3 = 0.f;
    int j = 0;
    for (; j + 4 <= c; j += 4) {
        int i0 = adj[o + j + 0];
        int i1 = adj[o + j + 1];
        int i2 = adj[o + j + 2];
        int i3 = adj[o + j + 3];
        bool v0 = (unsigned)i0 < N_NODES, v1 = (unsigned)i1 < N_NODES;
        bool v2 = (unsigned)i2 < N_NODES, v3 = (unsigned)i3 < N_NODES;
        if (BF16) {
            const unsigned int* xu = (const unsigned int*)x;
            unsigned int w0 = xu[(v0 ? i0 : 0) * 64 + lane];
            unsigned int w1 = xu[(v1 ? i1 : 0) * 64 + lane];
            unsigned int w2 = xu[(v2 ? i2 : 0) * 64 + lane];
            unsigned int w3 = xu[(v3 ? i3 : 0) * 64 + lane];
            lo0 += v0 ? scrub(bf2f(w0 & 0xffffu)) : 0.f;
            hi0 += v0 ? scrub(bf2f(w0 >> 16)) : 0.f;
            lo1 += v1 ? scrub(bf2f(w1 & 0xffffu)) : 0.f;
            hi1 += v1 ? scrub(bf2f(w1 >> 16)) : 0.f;
            lo2 += v2 ? scrub(bf2f(w2 & 0xffffu)) : 0.f;
            hi2 += v2 ? scrub(bf2f(w2 >> 16)) : 0.f;
            lo3 += v3 ? scrub(bf2f(w3 & 0xffffu)) : 0.f;
            hi3 += v3 ? scrub(bf2f(w3 >> 16)) : 0.f;
        } else {
            const float* xf = (const float*)x;
            lo0 += v0 ? scrub(xf[i0 * 128 + 2 * lane]) : 0.f;
            hi0 += v0 ? scrub(xf[i0 * 128 + 2 * lane + 1]) : 0.f;
            lo1 += v1 ? scrub(xf[i1 * 128 + 2 * lane]) : 0.f;
            hi1 += v1 ? scrub(xf[i1 * 128 + 2 * lane + 1]) : 0.f;
            lo2 += v2 ? scrub(xf[i2 * 128 + 2 * lane]) : 0.f;
            hi2 += v2 ? scrub(xf[i2 * 128 + 2 * lane + 1]) : 0.f;
            lo3 += v3 ? scrub(xf[i3 * 128 + 2 * lane]) : 0.f;
            hi3 += v3 ? scrub(xf[i3 * 128 + 2 * lane + 1]) : 0.f;
        }
    }
    for (; j < c; ++j) {
        int idx = adj[o + j];
        bool v = (unsigned)idx < N_NODES;
        if (BF16) {
            unsigned int w = ((const unsigned int*)x)[(v ? idx : 0) * 64 + lane];
            lo0 += v ? scrub(bf2f(w & 0xffffu)) : 0.f;
            hi0 += v ? scrub(bf2f(w >> 16)) : 0.f;
        } else {
            const float* xf = (const float*)x;
            lo0 += v ? scrub(xf[idx * 128 + 2 * lane]) : 0.f;
            hi0 += v ? scrub(xf[idx * 128 + 2 * lane + 1]) : 0.f;
        }
    }
    float inv = 0.5f / (float)(c > 0 ? c : 1);
    *out_lo = ((lo0 + lo1) + (lo2 + lo3)) * inv;
    *out_hi = ((hi0 + hi1) + (hi2 + hi3)) * inv;
}

template <bool BF16>
__device__ void aggemm_body(const void* x, const int* off0, const int* adj0,
                            const int* off1, const int* adj1,
                            const void* Wself, const void* Ws2d, const void* Wd2s,
                            const void* bself, const void* bs2d, const void* bd2s,
                            void* out) {
    __shared__ float agg0[4][128];
    __shared__ float agg1[4][128];
    __shared__ float xr[4][128];
    int tid = threadIdx.x;

    // ---- phase 1: 4 nodes, 64 lanes each, 2 dims per lane ----
    {
        int nl = tid >> 6;          // node_loc 0..3
        int lane = tid & 63;        // dims 2*lane, 2*lane+1
        int m = blockIdx.x * 4 + nl;
        float lo, hi;
        {
            int o = off0[m];
            int c = off0[m + 1] - o;
            if (o < 0) o = 0;
            if (c < 0) c = 0;
            gather_pair<BF16>(x, adj0, o, c, lane, &lo, &hi);
            agg0[nl][2 * lane] = lo;
            agg0[nl][2 * lane + 1] = hi;
        }
        {
            int o = off1[m];
            int c = off1[m + 1] - o;
            if (o < 0) o = 0;
            if (c < 0) c = 0;
            gather_pair<BF16>(x, adj1, o, c, lane, &lo, &hi);
            agg1[nl][2 * lane] = lo;
            agg1[nl][2 * lane + 1] = hi;
        }
        if (BF16) {
            unsigned int w = ((const unsigned int*)x)[m * 64 + lane];
            xr[nl][2 * lane] = scrub(bf2f(w & 0xffffu));
            xr[nl][2 * lane + 1] = scrub(bf2f(w >> 16));
        } else {
            const float* xf = (const float*)x;
            xr[nl][2 * lane] = scrub(xf[m * 128 + 2 * lane]);
            xr[nl][2 * lane + 1] = scrub(xf[m * 128 + 2 * lane + 1]);
        }
    }
    __syncthreads();

    // ---- phase 2: each thread -> rows {mloc, mloc+2}, one W load serves both
    int mloc = tid >> 7;            // 0..1
    int n = tid & 127;
    int r0 = mloc, r1 = mloc + 2;
    int m0 = blockIdx.x * 4 + r0;
    int m1 = blockIdx.x * 4 + r1;

    float bias = ldf<BF16>(bself, n) + 0.5f * (ldf<BF16>(bs2d, n) + ldf<BF16>(bd2s, n));
    float pA = bias, pB = 0.f;      // row r0, 2 chains
    float qA = bias, qB = 0.f;      // row r1, 2 chains
    for (int k = 0; k < 128; k += 2) {
        float ws0 = ldf<BF16>(Wself, (k + 0) * 128 + n);
        float ws1 = ldf<BF16>(Wself, (k + 1) * 128 + n);
        float wa0 = ldf<BF16>(Ws2d, (k + 0) * 128 + n);
        float wa1 = ldf<BF16>(Ws2d, (k + 1) * 128 + n);
        float wb0 = ldf<BF16>(Wd2s, (k + 0) * 128 + n);
        float wb1 = ldf<BF16>(Wd2s, (k + 1) * 128 + n);
        pA += xr[r0][k] * ws0;       pB += xr[r0][k + 1] * ws1;
        pA += agg0[r0][k] * wa0;     pB += agg0[r0][k + 1] * wa1;
        pA += agg1[r0][k] * wb0;     pB += agg1[r0][k + 1] * wb1;
        qA += xr[r1][k] * ws0;       qB += xr[r1][k + 1] * ws1;
        qA += agg0[r1][k] * wa0;     qB += agg0[r1][k + 1] * wa1;
        qA += agg1[r1][k] * wb0;     qB += agg1[r1][k + 1] * wb1;
    }
    if (BF16) {
        ((unsigned short*)out)[m0 * 128 + n] = f2bf(pA + pB);
        ((unsigned short*)out)[m1 * 128 + n] = f2bf(qA + qB);
    } else {
        ((float*)out)[m0 * 128 + n] = pA + pB;
        ((float*)out)[m1 * 128 + n] = qA + qB;
    }
}

__global__ __launch_bounds__(256) void k_aggemm(const void* x, const int* dflag,
                                                const int* off0, const int* adj0,
                                                const int* off1, const int* adj1,
                                                const void* Wself, const void* Ws2d,
                                                const void* Wd2s,
                                                const void* bself, const void* bs2d,
                                                const void* bd2s, void* out) {
    if (dflag[0])
        aggemm_body<true>(x, off0, adj0, off1, adj1, Wself, Ws2d, Wd2s,
                          bself, bs2d, bd2s, out);
    else
        aggemm_body<false>(x, off0, adj0, off1, adj1, Wself, Ws2d, Wd2s,
                           bself, bs2d, bd2s, out);
}

// ---- sentinel: decodable failure diagnosis via absmax ----
__global__ __launch_bounds__(256) void k_sentinel(float* __restrict__ out, float v) {
    int i = blockIdx.x * 256 + threadIdx.x;
    if (i < 640000) out[i] = v;
}

extern "C" void kernel_launch(void* const* d_in, const int* in_sizes, int n_in,
                              void* d_out, int out_size, void* d_ws, size_t ws_size,
                              hipStream_t stream) {
    const void* x = d_in[0];
    const int* ei = (const int*)d_in[1];
    const void* Ws2d = d_in[2];
    const void* bs2d = d_in[3];
    const void* Wd2s = d_in[4];
    const void* bd2s = d_in[5];
    const void* Wself = d_in[6];
    const void* bself = d_in[7];

    bool sizes_ok = (n_in == 8)
        && in_sizes[0] == 1280000
        && (in_sizes[1] == 1280000 || in_sizes[1] == 2560000)
        && in_sizes[2] == 16384 && in_sizes[3] == 128
        && in_sizes[4] == 16384 && in_sizes[5] == 128
        && in_sizes[6] == 16384 && in_sizes[7] == 128
        && out_size == 1280000;
    size_t ws_need = (size_t)(40032 + 2 * 640000) * 4;   // 5.28 MB (proven r10/r11)
    if (ws_size < ws_need) {
        k_sentinel<<<2500, 256, 0, stream>>>((float*)d_out, 1000.0f);
        return;
    }
    if (!sizes_ok) {
        k_sentinel<<<2500, 256, 0, stream>>>((float*)d_out, 2000.0f);
        return;
    }

    int* ws = (int*)d_ws;
    int* cnt0  = ws;             // [10000]
    int* cnt1  = ws + 10000;     // [10000]
    int* dflag = ws + 20001;     // [1]
    int* off0  = ws + 20016;     // [10001]
    int* off1  = ws + 30017;     // [10001]
    int* adj0  = ws + 40032;     // [640000]
    int* adj1  = ws + 680032;    // [640000]

    hipMemsetAsync(ws, 0, 20002 * sizeof(int), stream);  // cnt0, cnt1, flags

    k_count<<<N_EDGES / 256, 256, 0, stream>>>(ei, cnt0, cnt1);
    k_scan<<<2, 1024, 0, stream>>>(cnt0, off0, (const unsigned int*)x, dflag);
    k_fill_both<<<N_EDGES / 256, 256, 0, stream>>>(ei, off0, off1,
                                                   cnt0, cnt1, adj0, adj1);
    k_aggemm<<<N_NODES / 4, 256, 0, stream>>>(x, dflag, off0, adj0, off1, adj1,
                                              Wself, Ws2d, Wd2s,
                                              bself, bs2d, bd2s, d_out);
}

// Round 13
// 324.144 us; speedup vs baseline: 1.2511x; 1.2511x over previous
//
#include <hip/hip_runtime.h>

#define N_NODES 10000
#define N_EDGES 640000

__device__ __forceinline__ float bf2f(unsigned int u) {
    union { unsigned int i; float f; } v; v.i = u << 16; return v.f;
}
__device__ __forceinline__ unsigned short f2bf(float f) {
    union { float f; unsigned int i; } v; v.f = f;
    unsigned int x = v.i;
    return (unsigned short)((x + 0x7fffu + ((x >> 16) & 1u)) >> 16);
}
__device__ __forceinline__ float scrub(float v) {
    return (v == v && fabsf(v) < 1e6f) ? v : 0.f;
}

// dtype-branched load of float tensor element i
template <bool BF16>
__device__ __forceinline__ float ldf(const void* p, int i) {
    if (BF16) return scrub(bf2f(((const unsigned short*)p)[i]));
    else      return scrub(((const float*)p)[i]);
}

// ---- K_probe: sampled edge-dtype + f32/bf16 stats (r9/r10-proven) ----
__global__ __launch_bounds__(256) void k_probe(const unsigned int* __restrict__ xw,
                                               const int* __restrict__ ei,
                                               int* __restrict__ dflag,
                                               int* __restrict__ eflag) {
    int gid = blockIdx.x * 256 + threadIdx.x;
    if (gid < 8192 && ei[2 * gid + 1] != 0) eflag[0] = 1;  // benign identical-value race
    if (blockIdx.x == 0) {
        __shared__ int cnt_s;
        if (threadIdx.x == 0) cnt_s = 0;
        __syncthreads();
        int good = 0;
        for (int i = threadIdx.x; i < 4096; i += 256) {
            unsigned int e = (xw[i] >> 7) & 0xFFu;
            if (e >= 96u && e <= 160u) good++;
        }
        atomicAdd(&cnt_s, good);
        __syncthreads();
        if (threadIdx.x == 0) dflag[0] = (cnt_s > 2458) ? 1 : 0;   // >60% -> bf16
    }
}

// ---- K1: degree counts (r10-proven: scalar eflag read) ----
__global__ __launch_bounds__(256) void k_count(const int* __restrict__ ei,
                                               const int* __restrict__ eflag,
                                               int* __restrict__ cnt0,
                                               int* __restrict__ cnt1) {
    int e = blockIdx.x * 256 + threadIdx.x;        // grid exactly covers N_EDGES
    int step = eflag[0] ? 1 : 2;
    int s = ei[e * step];
    int d = ei[N_EDGES * step + e * step];
    if ((unsigned)s >= N_NODES || (unsigned)d >= N_NODES) return;
    atomicAdd(&cnt0[d], 1);   // dir0: aggregate x[src] at dst
    atomicAdd(&cnt1[s], 1);   // dir1: aggregate x[dst] at src
}

// ---- K2: shfl exclusive scan + sentinel (r10-proven) ----
__global__ __launch_bounds__(1024) void k_scan(const int* __restrict__ cnt_base,
                                               int* __restrict__ off_base) {
    const int* cnt = cnt_base + blockIdx.x * N_NODES;
    int* off = off_base + blockIdx.x * (N_NODES + 1);
    __shared__ int wsum[16];
    __shared__ int wexc[16];
    int t = threadIdx.x;
    int lane = t & 63, wid = t >> 6;
    int c[10];
    int s = 0;
    int base_i = t * 10;
#pragma unroll
    for (int i = 0; i < 10; ++i) {
        int idx = base_i + i;
        c[i] = (idx < N_NODES) ? cnt[idx] : 0;
        s += c[i];
    }
    int v = s;
    for (int d = 1; d < 64; d <<= 1) {
        int u = __shfl_up(v, d, 64);
        if (lane >= d) v += u;
    }
    if (lane == 63) wsum[wid] = v;
    __syncthreads();
    if (t < 16) {
        int acc = 0;
        for (int i = 0; i < t; ++i) acc += wsum[i];
        wexc[t] = acc;
    }
    __syncthreads();
    int run = wexc[wid] + (v - s);
#pragma unroll
    for (int i = 0; i < 10; ++i) {
        int idx = base_i + i;
        if (idx < N_NODES) off[idx] = run;
        run += c[i];
    }
    if (t == 1023) off[N_NODES] = run;   // total (sentinel)
}

// ---- K3: fill both CSR buckets, one ei pass (r10-proven) ----
__global__ __launch_bounds__(256) void k_fill_both(const int* __restrict__ ei,
                                                   const int* __restrict__ eflag,
                                                   const int* __restrict__ off0,
                                                   const int* __restrict__ off1,
                                                   int* __restrict__ cnt0,
                                                   int* __restrict__ cnt1,
                                                   int* __restrict__ adj0,
                                                   int* __restrict__ adj1) {
    int e = blockIdx.x * 256 + threadIdx.x;
    int step = eflag[0] ? 1 : 2;
    int s = ei[e * step];
    int d = ei[N_EDGES * step + e * step];
    if ((unsigned)s >= N_NODES || (unsigned)d >= N_NODES) return;
    int p0 = atomicSub(&cnt0[d], 1) - 1;   // unique slot in [0, cnt0[d])
    int p1 = atomicSub(&cnt1[s], 1) - 1;
    adj0[off0[d] + p0] = s;
    adj1[off1[s] + p1] = d;
}

// ---- K4: dual-direction fused aggemm (byte-identical to passing r11) ----
template <bool BF16>
__device__ __forceinline__ float gather_half_mean(const void* x, const int* adj,
                                                  int o, int c, int n) {
    float a0 = 0.f, a1 = 0.f, a2 = 0.f, a3 = 0.f;
    float a4 = 0.f, a5 = 0.f, a6 = 0.f, a7 = 0.f;
    int j = 0;
    for (; j + 8 <= c; j += 8) {
        int i0 = adj[o + j + 0];
        int i1 = adj[o + j + 1];
        int i2 = adj[o + j + 2];
        int i3 = adj[o + j + 3];
        int i4 = adj[o + j + 4];
        int i5 = adj[o + j + 5];
        int i6 = adj[o + j + 6];
        int i7 = adj[o + j + 7];
        bool v0 = (unsigned)i0 < N_NODES, v1 = (unsigned)i1 < N_NODES;
        bool v2 = (unsigned)i2 < N_NODES, v3 = (unsigned)i3 < N_NODES;
        bool v4 = (unsigned)i4 < N_NODES, v5 = (unsigned)i5 < N_NODES;
        bool v6 = (unsigned)i6 < N_NODES, v7 = (unsigned)i7 < N_NODES;
        float f0 = ldf<BF16>(x, (v0 ? i0 : 0) * 128 + n);
        float f1 = ldf<BF16>(x, (v1 ? i1 : 0) * 128 + n);
        float f2 = ldf<BF16>(x, (v2 ? i2 : 0) * 128 + n);
        float f3 = ldf<BF16>(x, (v3 ? i3 : 0) * 128 + n);
        float f4 = ldf<BF16>(x, (v4 ? i4 : 0) * 128 + n);
        float f5 = ldf<BF16>(x, (v5 ? i5 : 0) * 128 + n);
        float f6 = ldf<BF16>(x, (v6 ? i6 : 0) * 128 + n);
        float f7 = ldf<BF16>(x, (v7 ? i7 : 0) * 128 + n);
        a0 += v0 ? f0 : 0.f;
        a1 += v1 ? f1 : 0.f;
        a2 += v2 ? f2 : 0.f;
        a3 += v3 ? f3 : 0.f;
        a4 += v4 ? f4 : 0.f;
        a5 += v5 ? f5 : 0.f;
        a6 += v6 ? f6 : 0.f;
        a7 += v7 ? f7 : 0.f;
    }
    for (; j < c; ++j) {
        int idx = adj[o + j];
        if ((unsigned)idx < N_NODES) a0 += ldf<BF16>(x, idx * 128 + n);
    }
    float asum = ((a0 + a1) + (a2 + a3)) + ((a4 + a5) + (a6 + a7));
    return asum * (0.5f / (float)(c > 0 ? c : 1));
}

template <bool BF16>
__device__ void aggemm_body(const void* x, const int* off0, const int* adj0,
                            const int* off1, const int* adj1,
                            const void* Wself, const void* Ws2d, const void* Wd2s,
                            const void* bself, const void* bs2d, const void* bd2s,
                            void* out) {
    __shared__ float agg0[2][128];
    __shared__ float agg1[2][128];
    __shared__ float xr[2][128];
    int tid = threadIdx.x;
    int mloc = tid >> 7;
    int n = tid & 127;
    int m = blockIdx.x * 2 + mloc;

    {
        int o = off0[m];
        int c = off0[m + 1] - o;
        if (o < 0) o = 0;
        if (c < 0) c = 0;
        agg0[mloc][n] = gather_half_mean<BF16>(x, adj0, o, c, n);
    }
    {
        int o = off1[m];
        int c = off1[m + 1] - o;
        if (o < 0) o = 0;
        if (c < 0) c = 0;
        agg1[mloc][n] = gather_half_mean<BF16>(x, adj1, o, c, n);
    }
    xr[mloc][n] = ldf<BF16>(x, m * 128 + n);
    __syncthreads();

    float accA = ldf<BF16>(bself, n) + 0.5f * (ldf<BF16>(bs2d, n) + ldf<BF16>(bd2s, n));
    float accB = 0.f, accC = 0.f, accD = 0.f;
    for (int k = 0; k < 128; k += 4) {
        accA += xr[mloc][k + 0] * ldf<BF16>(Wself, (k + 0) * 128 + n);
        accB += xr[mloc][k + 1] * ldf<BF16>(Wself, (k + 1) * 128 + n);
        accC += xr[mloc][k + 2] * ldf<BF16>(Wself, (k + 2) * 128 + n);
        accD += xr[mloc][k + 3] * ldf<BF16>(Wself, (k + 3) * 128 + n);
        accA += agg0[mloc][k + 0] * ldf<BF16>(Ws2d, (k + 0) * 128 + n);
        accB += agg0[mloc][k + 1] * ldf<BF16>(Ws2d, (k + 1) * 128 + n);
        accC += agg0[mloc][k + 2] * ldf<BF16>(Ws2d, (k + 2) * 128 + n);
        accD += agg0[mloc][k + 3] * ldf<BF16>(Ws2d, (k + 3) * 128 + n);
        accA += agg1[mloc][k + 0] * ldf<BF16>(Wd2s, (k + 0) * 128 + n);
        accB += agg1[mloc][k + 1] * ldf<BF16>(Wd2s, (k + 1) * 128 + n);
        accC += agg1[mloc][k + 2] * ldf<BF16>(Wd2s, (k + 2) * 128 + n);
        accD += agg1[mloc][k + 3] * ldf<BF16>(Wd2s, (k + 3) * 128 + n);
    }
    float acc = (accA + accB) + (accC + accD);
    if (BF16) ((unsigned short*)out)[m * 128 + n] = f2bf(acc);
    else      ((float*)out)[m * 128 + n] = acc;
}

__global__ __launch_bounds__(256) void k_aggemm(const void* x, const int* dflag,
                                                const int* off0, const int* adj0,
                                                const int* off1, const int* adj1,
                                                const void* Wself, const void* Ws2d,
                                                const void* Wd2s,
                                                const void* bself, const void* bs2d,
                                                const void* bd2s, void* out) {
    if (dflag[0])
        aggemm_body<true>(x, off0, adj0, off1, adj1, Wself, Ws2d, Wd2s,
                          bself, bs2d, bd2s, out);
    else
        aggemm_body<false>(x, off0, adj0, off1, adj1, Wself, Ws2d, Wd2s,
                           bself, bs2d, bd2s, out);
}

// ---- sentinel: decodable failure diagnosis via absmax ----
__global__ __launch_bounds__(256) void k_sentinel(float* __restrict__ out, float v) {
    int i = blockIdx.x * 256 + threadIdx.x;
    if (i < 640000) out[i] = v;
}

extern "C" void kernel_launch(void* const* d_in, const int* in_sizes, int n_in,
                              void* d_out, int out_size, void* d_ws, size_t ws_size,
                              hipStream_t stream) {
    const void* x = d_in[0];
    const int* ei = (const int*)d_in[1];
    const void* Ws2d = d_in[2];
    const void* bs2d = d_in[3];
    const void* Wd2s = d_in[4];
    const void* bd2s = d_in[5];
    const void* Wself = d_in[6];
    const void* bself = d_in[7];

    bool sizes_ok = (n_in == 8)
        && in_sizes[0] == 1280000
        && (in_sizes[1] == 1280000 || in_sizes[1] == 2560000)
        && in_sizes[2] == 16384 && in_sizes[3] == 128
        && in_sizes[4] == 16384 && in_sizes[5] == 128
        && in_sizes[6] == 16384 && in_sizes[7] == 128
        && out_size == 1280000;
    size_t ws_need = (size_t)(40032 + 2 * 640000) * 4;   // 5.28 MB (proven r10/r11)
    if (ws_size < ws_need) {
        k_sentinel<<<2500, 256, 0, stream>>>((float*)d_out, 1000.0f);
        return;
    }
    if (!sizes_ok) {
        k_sentinel<<<2500, 256, 0, stream>>>((float*)d_out, 2000.0f);
        return;
    }

    int* ws = (int*)d_ws;
    int* cnt0  = ws;             // [10000]
    int* cnt1  = ws + 10000;     // [10000]
    int* eflag = ws + 20000;     // [1]
    int* dflag = ws + 20001;     // [1]
    int* off0  = ws + 20016;     // [10001]
    int* off1  = ws + 30017;     // [10001]
    int* adj0  = ws + 40032;     // [640000]
    int* adj1  = ws + 680032;    // [640000]

    hipMemsetAsync(ws, 0, 20002 * sizeof(int), stream);  // cnt0, cnt1, flags

    k_probe<<<32, 256, 0, stream>>>((const unsigned int*)x, ei, dflag, eflag);
    k_count<<<N_EDGES / 256, 256, 0, stream>>>(ei, eflag, cnt0, cnt1);
    k_scan<<<2, 1024, 0, stream>>>(cnt0, off0);
    k_fill_both<<<N_EDGES / 256, 256, 0, stream>>>(ei, eflag, off0, off1,
                                                   cnt0, cnt1, adj0, adj1);
    k_aggemm<<<N_NODES / 2, 256, 0, stream>>>(x, dflag, off0, adj0, off1, adj1,
                                              Wself, Ws2d, Wd2s,
                                              bself, bs2d, bd2s, d_out);
}